// Round 5
// baseline (95.754 us; speedup 1.0000x reference)
//
#include <hip/hip_runtime.h>
#include <math.h>

// Filtered Back Projection, B=2, A=181, L=512, P=1024.
// ws layout (floats):
//   [0,1024)        filt
//   [1024,2048)     hr (real impulse response)
//   [2048,2410)     cs interleaved: {cos,sin}(angle+pi/2) per angle (float2)
//   [4096,189440)   sino_f interleaved: [a][pos][{img0,img1}]  (181*512*2)
#define OFF_FILT 0
#define OFF_HR   1024
#define OFF_CS   2048
#define OFF_SF   4096

#define PAD   108
#define ROWE  728          // PAD + 512 + PAD
#define CHUNK 8
#define HALFE (CHUNK * ROWE)   // float2 elements per buffer (5824)

// cos(2*pi*x) -- v_cos_f32 takes revolutions
__device__ __forceinline__ float cos2pi(float x) {
  return __builtin_amdgcn_cosf(x);
}

// async global->LDS, 16B per lane. Requirement (guide §5): within a wave the
// LDS dest must be uniform-base + lane*16 -- our staging layout satisfies
// this exactly (r0 wave-uniform, col = base + lane).
typedef unsigned int u32;
__device__ __forceinline__ void gload_lds16(const void* g, void* l) {
  __builtin_amdgcn_global_load_lds(
      (const __attribute__((address_space(1))) u32*)g,
      (__attribute__((address_space(3))) u32*)l, 16, 0, 0);
}

// ---- filt[k] = ramp[k]*hann_shift[k]; wave-per-output, v_cos phases -------
__global__ __launch_bounds__(256) void k_filt(const float* __restrict__ angles,
                                              float* __restrict__ ws) {
  const int t = threadIdx.x & 63;
  const int k = blockIdx.x * 4 + (threadIdx.x >> 6);   // 0..1023
  float acc = 0.f;
#pragma unroll
  for (int q = 0; q < 8; q++) {
    int tt = t + 64 * q;
    int n = (tt < 256) ? (2 * tt + 1) : (1023 - 2 * tt);
    float pin = 3.14159265358979f * (float)n;
    float cf = -1.0f / (pin * pin);
    int r = ((2 * tt + 1) * k) & 1023;
    acc = fmaf(cf, cos2pi((float)r * (1.0f / 1024.0f)), acc);
  }
#pragma unroll
  for (int o = 32; o; o >>= 1) acc += __shfl_down(acc, o, 64);
  if (t == 0) {
    float ramp = 0.5f + 2.0f * acc;
    int ks = (k + 512) & 1023;                         // fftshift
    float hann = 0.5f - 0.5f * cos2pi((float)ks * (1.0f / 1023.0f));
    ws[OFF_FILT + k] = ramp * hann;
  }
  if (blockIdx.x == 0 && threadIdx.x < 181) {          // angle trig, interleaved
    float th = angles[threadIdx.x] + 1.5707963267948966f;
    ws[OFF_CS + 2 * threadIdx.x]     = cosf(th);
    ws[OFF_CS + 2 * threadIdx.x + 1] = sinf(th);
  }
}

// ---- hr[m] = (1/1024) sum_k filt[k] cos(2*pi*k*m/1024); wave-per-output ---
__global__ __launch_bounds__(256) void k_hr(float* __restrict__ ws) {
  const int t = threadIdx.x & 63;
  const int m = blockIdx.x * 4 + (threadIdx.x >> 6);   // 0..1023
  float acc = 0.f;
  int r = (t * m) & 1023;
  const int step = (64 * m) & 1023;
#pragma unroll
  for (int q = 0; q < 16; q++) {
    acc = fmaf(ws[OFF_FILT + t + 64 * q],
               cos2pi((float)r * (1.0f / 1024.0f)), acc);
    r = (r + step) & 1023;
  }
#pragma unroll
  for (int o = 32; o; o >>= 1) acc += __shfl_down(acc, o, 64);
  if (t == 0) ws[OFF_HR + m] = acc * (1.0f / 1024.0f);
}

// ---- row circular conv, 8-wave split-K, block-per-(angle,half) ------------
__global__ __launch_bounds__(512) void k_conv(const float* __restrict__ sino,
                                              float* __restrict__ ws) {
  __shared__ float smem[6144];   // s0 512 | s1 512 | hr 1024 | part 4096
  const int tid = threadIdx.x;
  const int a = blockIdx.x >> 1;
  const int half = blockIdx.x & 1;
  const int lane = tid & 63;
  float* s_s0 = smem;
  float* s_s1 = smem + 512;
  float* s_hr = smem + 1024;
  float* part = smem + 2048;
  if (tid < 128) {
    ((float4*)s_s0)[tid] = ((const float4*)(sino + (size_t)a * 512))[tid];
  } else if (tid < 256) {
    ((float4*)s_s1)[tid - 128] =
        ((const float4*)(sino + (size_t)(181 + a) * 512))[tid - 128];
  } else {
    ((float4*)s_hr)[tid - 256] = ((const float4*)(ws + OFF_HR))[tid - 256];
  }
  __syncthreads();

  const int w = tid >> 6;                       // wave 0..7
  const int base = half * 256 + lane * 4;       // 4 output positions
  float acc0[4] = {0.f, 0.f, 0.f, 0.f};
  float acc1[4] = {0.f, 0.f, 0.f, 0.f};
  const float4* SH = (const float4*)s_hr;
  const float4* S0 = (const float4*)s_s0;
  const float4* S1 = (const float4*)s_s1;
#pragma unroll
  for (int ii = 0; ii < 8; ii++) {
    const int j8 = w * 64 + ii * 8;
    float4 sa0 = S0[j8 >> 2];
    float4 sb0 = S0[(j8 >> 2) + 1];
    float4 sa1 = S1[j8 >> 2];
    float4 sb1 = S1[(j8 >> 2) + 1];
    int wi = base - j8;
    float4 h0 = SH[((wi - 8) & 1023) >> 2];
    float4 h1 = SH[((wi - 4) & 1023) >> 2];
    float4 h2 = SH[(wi & 1023) >> 2];
    float qq[12] = {h0.x, h0.y, h0.z, h0.w, h1.x, h1.y,
                    h1.z, h1.w, h2.x, h2.y, h2.z, h2.w};
    float v0[8] = {sa0.x, sa0.y, sa0.z, sa0.w, sb0.x, sb0.y, sb0.z, sb0.w};
    float v1[8] = {sa1.x, sa1.y, sa1.z, sa1.w, sb1.x, sb1.y, sb1.z, sb1.w};
#pragma unroll
    for (int jj = 0; jj < 8; jj++) {
#pragma unroll
      for (int m = 0; m < 4; m++) {
        acc0[m] = fmaf(v0[jj], qq[8 + m - jj], acc0[m]);
        acc1[m] = fmaf(v1[jj], qq[8 + m - jj], acc1[m]);
      }
    }
  }
  float* pw = part + w * 512 + lane * 8;
  ((float4*)pw)[0] = make_float4(acc0[0], acc1[0], acc0[1], acc1[1]);
  ((float4*)pw)[1] = make_float4(acc0[2], acc1[2], acc0[3], acc1[3]);
  __syncthreads();
  float s = part[tid];
#pragma unroll
  for (int ww = 1; ww < 8; ww++) s += part[ww * 512 + tid];
  ws[OFF_SF + (size_t)a * 1024 + half * 512 + tid] = s;
}

// ---- backprojection: 2 rows per block (1024 thr), all 181 angles ----------
// Staging via global_load_lds (width 16) into a double-buffered LDS chunk:
// no VGPR round-trip, no ds_writes, ONE barrier per chunk (24 total vs 46).
// Loads for chunk c+1 fly during compute of chunk c; __syncthreads drains
// vmcnt+lgkmcnt. Wave-uniform circle skip retained.
__global__ __launch_bounds__(1024) void k_bp(const float* __restrict__ ws,
                                             const int* __restrict__ circ,
                                             float* __restrict__ out) {
  __shared__ float2 srow[2 * HALFE];           // 93184 B, 1 block/CU
  const int tid = threadIdx.x;
  const int j = tid & 511;                     // column
  const int ir = tid >> 9;                     // 0/1: which of the 2 rows
  const int i = blockIdx.x * 2 + ir;
  const float xc = (float)(i - 256);
  const float yc = (float)(j - 256);
  const float2* __restrict__ CS = (const float2*)(ws + OFF_CS);
  float acc0 = 0.f, acc1 = 0.f;

  // circle mask; wave-uniform skip flag for fully-masked waves
  const int circv = circ[0];
  const int dx = j - 256, dy = i - 256;
  const bool msk = (circv != 0) && (dx * dx + dy * dy > 65536);
  const bool wskip = (__all((int)msk) != 0);

  // zero guard bands of BOTH buffers once; interiors rewritten every chunk
  const float2 z2 = make_float2(0.f, 0.f);
  if (tid < PAD) {
#pragma unroll
    for (int r = 0; r < 2 * CHUNK; r++) srow[r * ROWE + tid] = z2;
  }
  if (tid < ROWE - PAD - 512) {
#pragma unroll
    for (int r = 0; r < 2 * CHUNK; r++) srow[r * ROWE + PAD + 512 + tid] = z2;
  }

  // staging slots: 8 rows x 256 float4 = 2048 per buffer; thread owns two:
  // (r0, col) and (r0+4, col). Per wave: r0 uniform, col = base + lane ->
  // LDS dest byte = base + 16*lane  (global_load_lds contiguity requirement).
  const int r0 = tid >> 8;                     // 0..3
  const int col = tid & 255;
  const float4* __restrict__ G4 = (const float4*)(ws + OFF_SF);
  float2* L0 = &srow[r0 * ROWE + PAD + col * 2];   // buffer-0 slot 0
  float2* L1 = L0 + 4 * ROWE;                      // buffer-0 slot 1

  // prologue: stage chunk 0 into buffer 0
  gload_lds16(&G4[min(r0, 180) * 256 + col], L0);
  gload_lds16(&G4[min(r0 + 4, 180) * 256 + col], L1);
  __syncthreads();                             // drains vmcnt: buf0 ready

  int A = 0;
  for (int c = 0; c < 23; c++) {               // 23*8 = 184 >= 181
    const int cur = c & 1;
    if (c < 22) {                              // async-stage chunk c+1 -> buf cur^1
      const int An = A + CHUNK;
      const int doff = cur ? 0 : HALFE;
      gload_lds16(&G4[min(An + r0, 180) * 256 + col], L0 + doff);
      gload_lds16(&G4[min(An + r0 + 4, 180) * 256 + col], L1 + doff);
    }
    if (!wskip) {                              // wave-uniform: masked waves idle
      const int nv = min(CHUNK, 181 - A);
      const float2* __restrict__ rb = srow + cur * HALFE;
#pragma unroll
      for (int r = 0; r < CHUNK; r++) {
        if (r >= nv) break;
        const float2 cs = CS[A + r];           // uniform -> s_load_dwordx2
        float u = fmaf(xc, cs.x, fmaf(yc, cs.y, 255.5f + (float)PAD));
        int b = (int)u;                        // u >= 1: trunc == floor
        float fr = __builtin_amdgcn_fractf(u); // v_fract_f32
        const float2* rp = rb + r * ROWE;
        float2 t0 = rp[b];
        float2 t1 = rp[b + 1];
        float w0 = 1.0f - fr;
        acc0 = fmaf(w0, t0.x, fmaf(fr, t1.x, acc0));
        acc1 = fmaf(w0, t0.y, fmaf(fr, t1.y, acc1));
      }
    }
    __syncthreads();     // all reads of buf[cur] done AND next-buf loads landed
    A += CHUNK;
  }
  const size_t o = (size_t)i * 512 + j;
  out[o] = msk ? 0.f : acc0;
  out[262144 + o] = msk ? 0.f : acc1;
}

extern "C" void kernel_launch(void* const* d_in, const int* in_sizes, int n_in,
                              void* d_out, int out_size, void* d_ws, size_t ws_size,
                              hipStream_t stream) {
  const float* sino = (const float*)d_in[0];    // (2,181,512) f32
  const float* angles = (const float*)d_in[1];  // (181,) f32
  const int* circ = (const int*)d_in[2];        // scalar int
  float* ws = (float*)d_ws;                     // ~758 KB used
  float* out = (float*)d_out;                   // (2,512,512) f32

  hipLaunchKernelGGL(k_filt, dim3(256), dim3(256),  0, stream, angles, ws);
  hipLaunchKernelGGL(k_hr,   dim3(256), dim3(256),  0, stream, ws);
  hipLaunchKernelGGL(k_conv, dim3(362), dim3(512),  0, stream, sino, ws);
  hipLaunchKernelGGL(k_bp,   dim3(256), dim3(1024), 0, stream, ws, circ, out);
}

// Round 6
// 89.548 us; speedup vs baseline: 1.0693x; 1.0693x over previous
//
#include <hip/hip_runtime.h>
#include <math.h>

// Filtered Back Projection, B=2, A=181, L=512, P=1024.
// ws layout (floats):
//   [0,1024)        filt
//   [1024,2048)     hr (real impulse response)
//   [2048,2410)     cs interleaved: {cos,sin}(angle+pi/2) per angle (float2)
//   [4096,189440)   sino_f interleaved: [a][pos][{img0,img1}]  (181*512*2)
#define OFF_FILT 0
#define OFF_HR   1024
#define OFF_CS   2048
#define OFF_SF   4096

#define PAD   108
#define ROWE  728          // PAD + 512 + PAD
#define CHUNK 8            // 8*728*8 = 46592 B LDS (1 block/CU)

// cos(2*pi*x) -- v_cos_f32 takes revolutions
__device__ __forceinline__ float cos2pi(float x) {
  return __builtin_amdgcn_cosf(x);
}

// ---- filt[k] = ramp[k]*hann_shift[k]; wave-per-output, v_cos phases -------
__global__ __launch_bounds__(256) void k_filt(const float* __restrict__ angles,
                                              float* __restrict__ ws) {
  const int t = threadIdx.x & 63;
  const int k = blockIdx.x * 4 + (threadIdx.x >> 6);   // 0..1023
  float acc = 0.f;
#pragma unroll
  for (int q = 0; q < 8; q++) {
    int tt = t + 64 * q;
    int n = (tt < 256) ? (2 * tt + 1) : (1023 - 2 * tt);
    float pin = 3.14159265358979f * (float)n;
    float cf = -1.0f / (pin * pin);
    int r = ((2 * tt + 1) * k) & 1023;
    acc = fmaf(cf, cos2pi((float)r * (1.0f / 1024.0f)), acc);
  }
#pragma unroll
  for (int o = 32; o; o >>= 1) acc += __shfl_down(acc, o, 64);
  if (t == 0) {
    float ramp = 0.5f + 2.0f * acc;
    int ks = (k + 512) & 1023;                         // fftshift
    float hann = 0.5f - 0.5f * cos2pi((float)ks * (1.0f / 1023.0f));
    ws[OFF_FILT + k] = ramp * hann;
  }
  if (blockIdx.x == 0 && threadIdx.x < 181) {          // angle trig, interleaved
    float th = angles[threadIdx.x] + 1.5707963267948966f;
    ws[OFF_CS + 2 * threadIdx.x]     = cosf(th);
    ws[OFF_CS + 2 * threadIdx.x + 1] = sinf(th);
  }
}

// ---- hr[m] = (1/1024) sum_k filt[k] cos(2*pi*k*m/1024); wave-per-output ---
__global__ __launch_bounds__(256) void k_hr(float* __restrict__ ws) {
  const int t = threadIdx.x & 63;
  const int m = blockIdx.x * 4 + (threadIdx.x >> 6);   // 0..1023
  float acc = 0.f;
  int r = (t * m) & 1023;
  const int step = (64 * m) & 1023;
#pragma unroll
  for (int q = 0; q < 16; q++) {
    acc = fmaf(ws[OFF_FILT + t + 64 * q],
               cos2pi((float)r * (1.0f / 1024.0f)), acc);
    r = (r + step) & 1023;
  }
#pragma unroll
  for (int o = 32; o; o >>= 1) acc += __shfl_down(acc, o, 64);
  if (t == 0) ws[OFF_HR + m] = acc * (1.0f / 1024.0f);
}

// ---- row circular conv, 8-wave split-K, block-per-(angle,half) ------------
__global__ __launch_bounds__(512) void k_conv(const float* __restrict__ sino,
                                              float* __restrict__ ws) {
  __shared__ float smem[6144];   // s0 512 | s1 512 | hr 1024 | part 4096
  const int tid = threadIdx.x;
  const int a = blockIdx.x >> 1;
  const int half = blockIdx.x & 1;
  const int lane = tid & 63;
  float* s_s0 = smem;
  float* s_s1 = smem + 512;
  float* s_hr = smem + 1024;
  float* part = smem + 2048;
  if (tid < 128) {
    ((float4*)s_s0)[tid] = ((const float4*)(sino + (size_t)a * 512))[tid];
  } else if (tid < 256) {
    ((float4*)s_s1)[tid - 128] =
        ((const float4*)(sino + (size_t)(181 + a) * 512))[tid - 128];
  } else {
    ((float4*)s_hr)[tid - 256] = ((const float4*)(ws + OFF_HR))[tid - 256];
  }
  __syncthreads();

  const int w = tid >> 6;                       // wave 0..7
  const int base = half * 256 + lane * 4;       // 4 output positions
  float acc0[4] = {0.f, 0.f, 0.f, 0.f};
  float acc1[4] = {0.f, 0.f, 0.f, 0.f};
  const float4* SH = (const float4*)s_hr;
  const float4* S0 = (const float4*)s_s0;
  const float4* S1 = (const float4*)s_s1;
#pragma unroll
  for (int ii = 0; ii < 8; ii++) {
    const int j8 = w * 64 + ii * 8;
    float4 sa0 = S0[j8 >> 2];
    float4 sb0 = S0[(j8 >> 2) + 1];
    float4 sa1 = S1[j8 >> 2];
    float4 sb1 = S1[(j8 >> 2) + 1];
    int wi = base - j8;
    float4 h0 = SH[((wi - 8) & 1023) >> 2];
    float4 h1 = SH[((wi - 4) & 1023) >> 2];
    float4 h2 = SH[(wi & 1023) >> 2];
    float qq[12] = {h0.x, h0.y, h0.z, h0.w, h1.x, h1.y,
                    h1.z, h1.w, h2.x, h2.y, h2.z, h2.w};
    float v0[8] = {sa0.x, sa0.y, sa0.z, sa0.w, sb0.x, sb0.y, sb0.z, sb0.w};
    float v1[8] = {sa1.x, sa1.y, sa1.z, sa1.w, sb1.x, sb1.y, sb1.z, sb1.w};
#pragma unroll
    for (int jj = 0; jj < 8; jj++) {
#pragma unroll
      for (int m = 0; m < 4; m++) {
        acc0[m] = fmaf(v0[jj], qq[8 + m - jj], acc0[m]);
        acc1[m] = fmaf(v1[jj], qq[8 + m - jj], acc1[m]);
      }
    }
  }
  float* pw = part + w * 512 + lane * 8;
  ((float4*)pw)[0] = make_float4(acc0[0], acc1[0], acc0[1], acc1[1]);
  ((float4*)pw)[1] = make_float4(acc0[2], acc1[2], acc0[3], acc1[3]);
  __syncthreads();
  float s = part[tid];
#pragma unroll
  for (int ww = 1; ww < 8; ww++) s += part[ww * 512 + tid];
  ws[OFF_SF + (size_t)a * 1024 + half * 512 + tid] = s;
}

// ---- backprojection: 2 rows per block (1024 thr), all 181 angles ----------
// PROVEN round-4 structure (88.8 us): register-prefetch staging, 2 barriers
// per 8-row chunk. (Round-5 global_load_lds dbuf regressed -7 us: the
// vmcnt(0) drain forced by __syncthreads stalls waves when compute/chunk is
// shorter than L2 latency.) Wave-uniform circle skip + fract retained; cs
// table interleaved (one s_load_dwordx2 per angle).
__global__ __launch_bounds__(1024) void k_bp(const float* __restrict__ ws,
                                             const int* __restrict__ circ,
                                             float* __restrict__ out) {
  __shared__ float2 srow[CHUNK * ROWE];        // 46592 B
  const int tid = threadIdx.x;
  const int j = tid & 511;                     // column
  const int ir = tid >> 9;                     // 0/1: which of the 2 rows
  const int i = blockIdx.x * 2 + ir;
  const float xc = (float)(i - 256);
  const float yc = (float)(j - 256);
  const float2* __restrict__ CS = (const float2*)(ws + OFF_CS);
  float acc0 = 0.f, acc1 = 0.f;

  // circle mask; wave-uniform skip flag for fully-masked waves
  const int circv = circ[0];
  const int dx = j - 256, dy = i - 256;
  const bool msk = (circv != 0) && (dx * dx + dy * dy > 65536);
  const bool wskip = (__all((int)msk) != 0);

  // zero guard bands once; interior rewritten every chunk
  const float2 z2 = make_float2(0.f, 0.f);
  if (tid < PAD) {
#pragma unroll
    for (int r = 0; r < CHUNK; r++) srow[r * ROWE + tid] = z2;
  }
  if (tid < ROWE - PAD - 512) {
#pragma unroll
    for (int r = 0; r < CHUNK; r++) srow[r * ROWE + PAD + 512 + tid] = z2;
  }

  // staging: 8 rows x 256 float4 slots = 2048; thread owns slots tid, tid+1024
  const int r0 = tid >> 8, r1 = r0 + 4;        // rows 0..3 and 4..7
  const int col = tid & 255;
  const float4* __restrict__ G = (const float4*)(ws + OFF_SF);
  float4* SW0 = (float4*)&srow[r0 * ROWE + PAD + col * 2];
  float4* SW1 = (float4*)&srow[r1 * ROWE + PAD + col * 2];
  const int rowcap = 180;

  int A = 0;
  float4 pre0 = G[min(r0, rowcap) * 256 + col];
  float4 pre1 = G[min(r1, rowcap) * 256 + col];

  for (int c = 0; c < 23; c++) {               // 23*8 = 184 >= 181
    __syncthreads();               // previous chunk fully consumed
    *SW0 = pre0;
    *SW1 = pre1;
    const int An = A + CHUNK;
    if (c < 22) {                  // prefetch next chunk (latency hidden)
      pre0 = G[min(An + r0, rowcap) * 256 + col];
      pre1 = G[min(An + r1, rowcap) * 256 + col];
    }
    __syncthreads();               // writes visible
    if (!wskip) {                  // wave-uniform: masked waves idle here
      const int nv = min(CHUNK, 181 - A);
#pragma unroll
      for (int r = 0; r < CHUNK; r++) {
        if (r >= nv) break;
        const float2 cs = CS[A + r];           // uniform -> s_load_dwordx2
        float u = fmaf(xc, cs.x, fmaf(yc, cs.y, 255.5f + (float)PAD));
        int b = (int)u;                        // u >= 1: trunc == floor
        float fr = __builtin_amdgcn_fractf(u); // v_fract_f32
        const float2* rp = &srow[r * ROWE];
        float2 t0 = rp[b];
        float2 t1 = rp[b + 1];
        float w0 = 1.0f - fr;
        acc0 = fmaf(w0, t0.x, fmaf(fr, t1.x, acc0));
        acc1 = fmaf(w0, t0.y, fmaf(fr, t1.y, acc1));
      }
    }
    A = An;
  }
  const size_t o = (size_t)i * 512 + j;
  out[o] = msk ? 0.f : acc0;
  out[262144 + o] = msk ? 0.f : acc1;
}

extern "C" void kernel_launch(void* const* d_in, const int* in_sizes, int n_in,
                              void* d_out, int out_size, void* d_ws, size_t ws_size,
                              hipStream_t stream) {
  const float* sino = (const float*)d_in[0];    // (2,181,512) f32
  const float* angles = (const float*)d_in[1];  // (181,) f32
  const int* circ = (const int*)d_in[2];        // scalar int
  float* ws = (float*)d_ws;                     // ~758 KB used
  float* out = (float*)d_out;                   // (2,512,512) f32

  hipLaunchKernelGGL(k_filt, dim3(256), dim3(256),  0, stream, angles, ws);
  hipLaunchKernelGGL(k_hr,   dim3(256), dim3(256),  0, stream, ws);
  hipLaunchKernelGGL(k_conv, dim3(362), dim3(512),  0, stream, sino, ws);
  hipLaunchKernelGGL(k_bp,   dim3(256), dim3(1024), 0, stream, ws, circ, out);
}